// Round 15
// baseline (134.904 us; speedup 1.0000x reference)
//
#include <hip/hip_runtime.h>
#include <math.h>

// Problem constants
#define Bsz 32
#define Nn  4096
#define DU  64
#define Dm  128

#define GRID_MLP 512    // 2 blocks/CU (68.1 KB LDS each); 8 waves = 4 pair-tiles per block

// workspace layout (float offsets)
#define WS_WKQ 0      // [2][128]  Wk-slice @ q per head
#define WS_BKQ 256    // [2]       bk-slice . q
#define WS_CNT 288    // [legacy region, zeroed, unused]
#define WS_WP  8576   // packed bf16 MFMA frag streams: 48 frags * 64 lanes * 8 ushort
#define WS_M   20864  // [256][128] prefolded Wv x Wo / 4096 (epilogue GEMM)
#define WS_VB  53632  // [2][128]   prefolded bv x Wo / 4096

#define H1STR 136     // shorts per h1 LDS row (128 + 8 pad), 16B-aligned

typedef short frag_ab __attribute__((ext_vector_type(8)));
typedef float frag_cd __attribute__((ext_vector_type(4)));

__device__ __forceinline__ unsigned short f2bf(float x) {   // RNE
    union { float f; unsigned int u; } c; c.f = x;
    unsigned int r = c.u + 0x7fffu + ((c.u >> 16) & 1u);
    return (unsigned short)(r >> 16);
}

// gelu(x) = x * sigmoid(2y) (exact identity for tanh-gelu), log2e folded
__device__ __forceinline__ float gelu_fast(float x) {
    float t = x * x;
    float a = x * fmaf(t, -0.1029432f, -2.3022081f);
    float e = __builtin_amdgcn_exp2f(a);
    return x * __builtin_amdgcn_rcpf(1.0f + e);
}

// Pair-local sync: the ONLY cross-wave hazards in the main loop (h1t, a2buf)
// are between the 2 waves of a pair. __syncthreads convoyed all 8 waves (6 of
// them needlessly) -- the measured 4x gap between per-iter critical path
// (~3-4K cy) and actual (~27K cy). LDS-flag sync waits pairwise only, and
// (unlike s_barrier's vmcnt(0) drain) leaves the u-prefetch in flight.
// lgkmcnt(0) orders this wave's LDS writes before the flag add; the empty asm
// after the spin blocks compiler hoisting of subsequent LDS reads.
__device__ __forceinline__ void pair_sync(int* flag, int target) {
    asm volatile("s_waitcnt lgkmcnt(0)" ::: "memory");
    if ((threadIdx.x & 63) == 0) atomicAdd(flag, 1);
    volatile int* vf = flag;
    while (*vf < target) {}
    asm volatile("" ::: "memory");
}

// K0: 32 blocks (unchanged from R14).
//   0..11  pack W1/W2 into MFMA frag bf16 streams (L2-hot for K1 staging)
//   12     qv/wkq/bkq (2-way parallel qv + concurrent heads)
//   13     zeroes legacy CNT region (harmless)
//   14..29 prefold M[hd][i] = sum_{c in head h} Wv[d][c] Wo[c][i] / 4096
//   30     vb[h][i]  = sum_{c in head h} bv[c] Wo[c][i] / 4096
//   31     out init: out[bb][i] = bo[i]  (K1 blocks atomicAdd contributions)
__global__ __launch_bounds__(256) void precompute_kernel(
    const float* __restrict__ embed, const float* __restrict__ Wq,
    const float* __restrict__ bq, const float* __restrict__ Wk,
    const float* __restrict__ bk, const float* __restrict__ W1,
    const float* __restrict__ W2, const float* __restrict__ Wv,
    const float* __restrict__ bv, const float* __restrict__ Wo,
    const float* __restrict__ bo, float* __restrict__ ws,
    float* __restrict__ out)
{
    __shared__ float qv[128];
    __shared__ float pp[256];
    const int tid = threadIdx.x;
    const int bid = blockIdx.x;

    if (bid < 12) {
        // frag f, lane L (q2=L>>4, n=L&15) holds W[ks*32+q2*8+j][nt*16+n], j=0..7
        const int e = bid * 256 + tid;     // 0..3071
        const int f = e >> 6, L = e & 63;
        const int q2 = L >> 4, n = L & 15;
        const float* src;
        int ks, nt;
        if (f < 16) { src = W1; ks = f >> 3;        nt = f & 7; }
        else        { src = W2; ks = (f - 16) >> 3; nt = (f - 16) & 7; }
        const int kb = ks * 32 + q2 * 8;
        const int c  = nt * 16 + n;
        unsigned int p[4];
        #pragma unroll
        for (int jj = 0; jj < 4; ++jj) {
            unsigned int lo = f2bf(src[(kb + 2 * jj)     * Dm + c]);
            unsigned int hi = f2bf(src[(kb + 2 * jj + 1) * Dm + c]);
            p[jj] = lo | (hi << 16);
        }
        ((uint4*)(ws + WS_WP))[e] = make_uint4(p[0], p[1], p[2], p[3]);
    } else if (bid == 12) {
        const int c = tid & 127, sg = tid >> 7;    // 2 segments
        {
            float s = 0.f;
            #pragma unroll 8
            for (int j0 = 0; j0 < 64; ++j0) {
                const int j = sg * 64 + j0;
                s += embed[j] * Wq[j * 128 + c];
            }
            pp[tid] = s;
        }
        __syncthreads();
        if (tid < 128) qv[tid] = bq[tid] + pp[tid] + pp[128 + tid];
        __syncthreads();
        {   // wkq: head = sg, both heads concurrent
            float s = 0.f;
            #pragma unroll 8
            for (int dh = 0; dh < 64; ++dh)
                s += Wk[c * 128 + sg * 64 + dh] * qv[sg * 64 + dh];
            ws[WS_WKQ + sg * 128 + c] = s;
        }
        if (tid < 2) {
            float s = 0.f;
            for (int dh = 0; dh < 64; ++dh) s += bk[tid * 64 + dh] * qv[tid * 64 + dh];
            ws[WS_BKQ + tid] = s;
        }
    } else if (bid == 13) {
        for (int idx = WS_CNT + tid; idx < WS_WP; idx += 256) ws[idx] = 0.f;
    } else if (bid < 30) {
        // M prefold: 16 blocks x 256 thr x 8 outputs = 32768 = 256x128
        const int base = (bid - 14) * 256 + tid;   // 0..4095
        #pragma unroll
        for (int k = 0; k < 8; ++k) {
            const int o  = base + 4096 * k;
            const int hd = o >> 7, i = o & 127;
            const int h = hd >> 7, d = hd & 127;
            float acc = 0.f;
            #pragma unroll 8
            for (int c64 = 0; c64 < 64; ++c64)
                acc += Wv[d * 128 + h * 64 + c64] * Wo[(h * 64 + c64) * 128 + i];
            ws[WS_M + o] = acc * (1.0f / 4096.0f);
        }
    } else if (bid == 30) {
        if (tid < 256) {
            const int h = tid >> 7, i = tid & 127;
            float acc = 0.f;
            #pragma unroll 8
            for (int c64 = 0; c64 < 64; ++c64)
                acc += bv[h * 64 + c64] * Wo[(h * 64 + c64) * 128 + i];
            ws[WS_VB + tid] = acc * (1.0f / 4096.0f);
        }
    } else {
        // out init: 32 batches x 128 = 4096 floats
        for (int o = tid; o < Bsz * 128; o += 256) out[o] = bo[o & 127];
    }
}

// K1: R14's verified chassis (132.7us e2e, best of session) with the 8
// in-loop __syncthreads replaced by PAIR-LOCAL LDS-flag syncs.
//   Hazard audit (pairwise sufficiency): a2buf reads(i) precede this wave's
//   sync1(i+1) add, which gates partner's publish(i+1); h1t layer-2 reads(i)
//   precede sync2(i) add, which gates partner's h1t write(i+1). No hazard
//   ever crosses a pair boundary. Staging + epilogue barriers stay block-wide.
//   Spin back-edges + rolled it-loop keep the scheduler-pressure bounds
//   (R2-R8 spill lesson). Per-block output-space epilogue unchanged (R14).
__global__ __launch_bounds__(512) void mlp_pool_kernel(
    const float* __restrict__ u,  const float* __restrict__ b1,
    const float* __restrict__ b2, float* __restrict__ ws,
    float* __restrict__ out)
{
    __shared__ short lds_w[48 * 512];          // 48 KB weight fragments (both layers)
    __shared__ short lds_h1[4 * 16 * H1STR];   // 4 pair tiles x 16 x 136 bf16 (17.4 KB)
    __shared__ float a2buf[4][16][2][2];       // [pair][row][head][half] (1 KB)
    __shared__ float b1_lds[128];
    __shared__ int   pflag[4];                 // per-pair sync counters

    const int tid  = threadIdx.x;
    const int wave = tid >> 6;
    const int lane = tid & 63;
    const int quad = lane >> 4;
    const int n15  = lane & 15;
    const int p    = wave >> 1;     // tile pair 0..3
    const int hf   = wave & 1;      // column half

    // stage all weight fragments global(L2) -> LDS (48 KB, 6 float4/thread)
    {
        const float4* src = (const float4*)(ws + WS_WP);
        float4* dst = (float4*)lds_w;
        #pragma unroll
        for (int i = 0; i < 6; ++i) dst[tid + 512 * i] = src[tid + 512 * i];
        if (tid < 128) b1_lds[tid] = b1[tid];
        if (tid < 4)   pflag[tid] = 0;
    }

    // per-lane constants for this wave's column half (layer-2 C layout)
    float b2c[4], wkq0[4], wkq1[4];
    #pragma unroll
    for (int nt = 0; nt < 4; ++nt) {
        const int c = hf * 64 + nt * 16 + n15;
        b2c[nt]  = b2[c];
        wkq0[nt] = ws[WS_WKQ + c];
        wkq1[nt] = ws[WS_WKQ + 128 + c];
    }
    const float bkq0 = ws[WS_BKQ];
    const float bkq1 = ws[WS_BKQ + 1];
    __syncthreads();               // block-wide: staging + pflag init visible

    const int bb = blockIdx.x >> 4;          // batch
    const int jb = blockIdx.x & 15;          // 256-row chunk within batch
    short* h1t = lds_h1 + p * 16 * H1STR;    // pair-shared tile
    int* pfl = &pflag[p];

    float s0p[4], s1p[4];
    #pragma unroll
    for (int nt = 0; nt < 4; ++nt) { s0p[nt] = 0.f; s1p[nt] = 0.f; }
    float aA0 = 0.f, aA1 = 0.f;

    // iter-0 u loads: lane (quad,n15) = row n15 of pair tile, k quad*8..+8, +32
    const float* ub = u + ((size_t)(bb * Nn + jb * 256 + p * 16 + n15)) * DU + quad * 8;
    float4 f0 = *(const float4*)(ub);
    float4 f1 = *(const float4*)(ub + 4);
    float4 f2 = *(const float4*)(ub + 32);
    float4 f3 = *(const float4*)(ub + 36);

    #pragma unroll 1            // keep rolled
    for (int it = 0; it < 4; ++it) {
        frag_ab a0, a1;
        a0[0] = (short)f2bf(f0.x); a0[1] = (short)f2bf(f0.y);
        a0[2] = (short)f2bf(f0.z); a0[3] = (short)f2bf(f0.w);
        a0[4] = (short)f2bf(f1.x); a0[5] = (short)f2bf(f1.y);
        a0[6] = (short)f2bf(f1.z); a0[7] = (short)f2bf(f1.w);
        a1[0] = (short)f2bf(f2.x); a1[1] = (short)f2bf(f2.y);
        a1[2] = (short)f2bf(f2.z); a1[3] = (short)f2bf(f2.w);
        a1[4] = (short)f2bf(f3.x); a1[5] = (short)f2bf(f3.y);
        a1[6] = (short)f2bf(f3.z); a1[7] = (short)f2bf(f3.w);

        // ---- layer 1, TRANSPOSED: D = W1^T-tile(16c x 64k) . u^T(64k x 16m)
        #pragma unroll
        for (int i = 0; i < 4; ++i) {
            const int ct = hf * 4 + i;
            float4 bi = *(const float4*)&b1_lds[ct * 16 + quad * 4];
            frag_cd acc = (frag_cd){bi.x, bi.y, bi.z, bi.w};       // bias folded
            frag_ab w0 = *(const frag_ab*)&lds_w[(ct)     * 512 + lane * 8];  // ks=0
            acc = __builtin_amdgcn_mfma_f32_16x16x32_bf16(w0, a0, acc, 0, 0, 0);
            frag_ab w1 = *(const frag_ab*)&lds_w[(8 + ct) * 512 + lane * 8];  // ks=1
            acc = __builtin_amdgcn_mfma_f32_16x16x32_bf16(w1, a1, acc, 0, 0, 0);
            unsigned int lo = (unsigned int)f2bf(gelu_fast(acc[0]))
                            | ((unsigned int)f2bf(gelu_fast(acc[1])) << 16);
            unsigned int hi = (unsigned int)f2bf(gelu_fast(acc[2]))
                            | ((unsigned int)f2bf(gelu_fast(acc[3])) << 16);
            *(uint2*)&h1t[n15 * H1STR + ct * 16 + quad * 4] = make_uint2(lo, hi);
        }
        pair_sync(pfl, 4 * it + 2);   // B1 (pair): both halves' h1 visible

        // prefetch next iter's u; stays in flight across pair-syncs (no vmcnt drain)
        if (it < 3) {
            const float* un = ub + (size_t)((it + 1) * 64) * DU;
            f0 = *(const float4*)(un);
            f1 = *(const float4*)(un + 4);
            f2 = *(const float4*)(un + 32);
            f3 = *(const float4*)(un + 36);
        }

        // ---- layer 2 (this half's 64 cols): M16 N64 K128, B from LDS
        frag_cd acc2[4];
        #pragma unroll
        for (int nt = 0; nt < 4; ++nt)
            acc2[nt] = (frag_cd){b2c[nt], b2c[nt], b2c[nt], b2c[nt]};  // bias folded
        #pragma unroll
        for (int ks = 0; ks < 4; ++ks) {
            frag_ab a2 = *(const frag_ab*)&h1t[n15 * H1STR + ks * 32 + quad * 8];
            #pragma unroll
            for (int nt = 0; nt < 4; ++nt) {
                frag_ab w2f = *(const frag_ab*)&lds_w[(16 + ks * 8 + hf * 4 + nt) * 512 + lane * 8];
                acc2[nt] = __builtin_amdgcn_mfma_f32_16x16x32_bf16(a2, w2f, acc2[nt], 0, 0, 0);
            }
        }

        // gelu -> z (this half) fp32 in registers
        #pragma unroll
        for (int nt = 0; nt < 4; ++nt) {
            #pragma unroll
            for (int r = 0; r < 4; ++r)
                acc2[nt][r] = gelu_fast(acc2[nt][r]);
        }

        // ---- half-alpha dots, reduce over n15 lanes, publish to a2buf
        float p0[4], p1[4];
        #pragma unroll
        for (int r = 0; r < 4; ++r) { p0[r] = 0.f; p1[r] = 0.f; }
        #pragma unroll
        for (int nt = 0; nt < 4; ++nt) {
            #pragma unroll
            for (int r = 0; r < 4; ++r) {
                p0[r] += acc2[nt][r] * wkq0[nt];
                p1[r] += acc2[nt][r] * wkq1[nt];
            }
        }
        #pragma unroll
        for (int r = 0; r < 4; ++r) {
            #pragma unroll
            for (int d = 1; d < 16; d <<= 1) {
                p0[r] += __shfl_xor(p0[r], d);
                p1[r] += __shfl_xor(p1[r], d);
            }
        }
        if (n15 == 0) {
            #pragma unroll
            for (int r = 0; r < 4; ++r) {
                const int row = quad * 4 + r;
                a2buf[p][row][0][hf] = p0[r];
                a2buf[p][row][1][hf] = p1[r];
            }
        }
        pair_sync(pfl, 4 * it + 4);   // B2 (pair): alpha halves visible; h1/a2buf reuse safe

        // ---- full alpha for my rows; accumulate S (my cols, z in acc2) and A
        #pragma unroll
        for (int r = 0; r < 4; ++r) {
            const int row = quad * 4 + r;
            const float al0 = a2buf[p][row][0][0] + a2buf[p][row][0][1] + bkq0;
            const float al1 = a2buf[p][row][1][0] + a2buf[p][row][1][1] + bkq1;
            #pragma unroll
            for (int nt = 0; nt < 4; ++nt) {
                s0p[nt] += al0 * acc2[nt][r];
                s1p[nt] += al1 * acc2[nt][r];
            }
            aA0 += al0; aA1 += al1;
        }
    }

    // cross-quad reduce: after xor16+xor32 ALL lanes hold the pair-total
    #pragma unroll
    for (int nt = 0; nt < 4; ++nt) {
        s0p[nt] += __shfl_xor(s0p[nt], 16); s0p[nt] += __shfl_xor(s0p[nt], 32);
        s1p[nt] += __shfl_xor(s1p[nt], 16); s1p[nt] += __shfl_xor(s1p[nt], 32);
    }
    aA0 += __shfl_xor(aA0, 16); aA0 += __shfl_xor(aA0, 32);
    aA1 += __shfl_xor(aA1, 16); aA1 += __shfl_xor(aA1, 32);

    // ---- per-block output-space epilogue (no counter, no finisher, no K2)
    // lds_h1 scratch (4352 floats): sw[0..1023]=[pair][256], aw[1024..1031],
    // Sb[1032..1287], part[1288..1799]
    float* sw   = (float*)lds_h1;
    float* aw   = sw + 1024;
    float* Sb   = sw + 1032;
    float* part = sw + 1288;

    __syncthreads();        // block-wide: all pairs done with h1t before reuse

    if (quad == 0) {        // 16 lanes x 4 nt x 2 heads per wave
        #pragma unroll
        for (int nt = 0; nt < 4; ++nt) {
            const int c = hf * 64 + nt * 16 + n15;
            sw[p * 256 + c]       = s0p[nt];
            sw[p * 256 + 128 + c] = s1p[nt];
        }
        if (hf == 0 && lane == 0) { aw[p * 2] = aA0; aw[p * 2 + 1] = aA1; }
    }
    __syncthreads();

    if (tid < 256)
        Sb[tid] = sw[tid] + sw[256 + tid] + sw[512 + tid] + sw[768 + tid];
    __syncthreads();

    {   // contrib = Sb(1x256) @ M(256x128), 4-way split-K over 512 threads
        const int i = tid & 127, seg = tid >> 7;
        float acc = 0.f;
        #pragma unroll 8
        for (int k = 0; k < 64; ++k) {
            const int hd = seg * 64 + k;
            acc += Sb[hd] * ws[WS_M + hd * 128 + i];
        }
        part[tid] = acc;
    }
    __syncthreads();

    if (tid < 128) {
        const float aT0 = aw[0] + aw[2] + aw[4] + aw[6];
        const float aT1 = aw[1] + aw[3] + aw[5] + aw[7];
        atomicAdd(&out[bb * 128 + tid],
                  part[tid] + part[128 + tid] + part[256 + tid] + part[384 + tid]
                  + aT0 * ws[WS_VB + tid] + aT1 * ws[WS_VB + 128 + tid]);
    }
}

extern "C" void kernel_launch(void* const* d_in, const int* in_sizes, int n_in,
                              void* d_out, int out_size, void* d_ws, size_t ws_size,
                              hipStream_t stream) {
    const float* u     = (const float*)d_in[0];
    // d_in[1] = x : unused by the reference
    const float* W1    = (const float*)d_in[2];
    const float* b1    = (const float*)d_in[3];
    const float* W2    = (const float*)d_in[4];
    const float* b2    = (const float*)d_in[5];
    const float* embed = (const float*)d_in[6];
    const float* Wq    = (const float*)d_in[7];
    const float* bq    = (const float*)d_in[8];
    const float* Wk    = (const float*)d_in[9];
    const float* bk    = (const float*)d_in[10];
    const float* Wv    = (const float*)d_in[11];
    const float* bv    = (const float*)d_in[12];
    const float* Wo    = (const float*)d_in[13];
    const float* bo    = (const float*)d_in[14];
    float* ws  = (float*)d_ws;
    float* out = (float*)d_out;

    hipLaunchKernelGGL(precompute_kernel, dim3(32), dim3(256), 0, stream,
                       embed, Wq, bq, Wk, bk, W1, W2, Wv, bv, Wo, bo, ws, out);
    hipLaunchKernelGGL(mlp_pool_kernel, dim3(GRID_MLP), dim3(512), 0, stream,
                       u, b1, b2, ws, out);
}

// Round 16
// 131.427 us; speedup vs baseline: 1.0265x; 1.0265x over previous
//
#include <hip/hip_runtime.h>
#include <math.h>

// Problem constants
#define Bsz 32
#define Nn  4096
#define DU  64
#define Dm  128

#define GRID_MLP 512    // 2 blocks/CU (68.1 KB LDS each); 8 waves = 4 pair-tiles per block

// workspace layout (float offsets)
#define WS_WKQ 0      // [2][128]  Wk-slice @ q per head
#define WS_BKQ 256    // [2]       bk-slice . q
#define WS_CNT 288    // [legacy region, zeroed, unused]
#define WS_WP  8576   // packed bf16 MFMA frag streams: 48 frags * 64 lanes * 8 ushort
#define WS_M   20864  // [256][128] prefolded Wv x Wo / 4096 (epilogue GEMM)
#define WS_VB  53632  // [2][128]   prefolded bv x Wo / 4096

#define H1STR 136     // shorts per h1 LDS row (128 + 8 pad), 16B-aligned

typedef short frag_ab __attribute__((ext_vector_type(8)));
typedef float frag_cd __attribute__((ext_vector_type(4)));

__device__ __forceinline__ unsigned short f2bf(float x) {   // RNE (K0 packer only)
    union { float f; unsigned int u; } c; c.f = x;
    unsigned int r = c.u + 0x7fffu + ((c.u >> 16) & 1u);
    return (unsigned short)(r >> 16);
}

// HW packed bf16 convert: D[15:0]=bf16rne(lo), D[31:16]=bf16rne(hi).
// 1 VALU inst replaces ~8 (two manual RNE bit-twiddles + pack). Same RNE
// rounding as f2bf -> bit-identical results. (T12/m240: no builtin on gfx950;
// m240's inline-asm warning applies to replacing compiler-FUSED scalar casts,
// not manual bit-ops.)
__device__ __forceinline__ unsigned int pk_bf16(float lo, float hi) {
    unsigned int r;
    asm("v_cvt_pk_bf16_f32 %0, %1, %2" : "=v"(r) : "v"(lo), "v"(hi));
    return r;
}

// gelu(x) = x * sigmoid(2y) (exact identity for tanh-gelu), log2e folded
__device__ __forceinline__ float gelu_fast(float x) {
    float t = x * x;
    float a = x * fmaf(t, -0.1029432f, -2.3022081f);
    float e = __builtin_amdgcn_exp2f(a);
    return x * __builtin_amdgcn_rcpf(1.0f + e);
}

// K0: 32 blocks (unchanged from R14).
//   0..11  pack W1/W2 into MFMA frag bf16 streams (L2-hot for K1 staging)
//   12     qv/wkq/bkq (2-way parallel qv + concurrent heads)
//   13     zeroes legacy CNT region (harmless)
//   14..29 prefold M[hd][i] = sum_{c in head h} Wv[d][c] Wo[c][i] / 4096
//   30     vb[h][i]  = sum_{c in head h} bv[c] Wo[c][i] / 4096
//   31     out init: out[bb][i] = bo[i]  (K1 blocks atomicAdd contributions)
__global__ __launch_bounds__(256) void precompute_kernel(
    const float* __restrict__ embed, const float* __restrict__ Wq,
    const float* __restrict__ bq, const float* __restrict__ Wk,
    const float* __restrict__ bk, const float* __restrict__ W1,
    const float* __restrict__ W2, const float* __restrict__ Wv,
    const float* __restrict__ bv, const float* __restrict__ Wo,
    const float* __restrict__ bo, float* __restrict__ ws,
    float* __restrict__ out)
{
    __shared__ float qv[128];
    __shared__ float pp[256];
    const int tid = threadIdx.x;
    const int bid = blockIdx.x;

    if (bid < 12) {
        // frag f, lane L (q2=L>>4, n=L&15) holds W[ks*32+q2*8+j][nt*16+n], j=0..7
        const int e = bid * 256 + tid;     // 0..3071
        const int f = e >> 6, L = e & 63;
        const int q2 = L >> 4, n = L & 15;
        const float* src;
        int ks, nt;
        if (f < 16) { src = W1; ks = f >> 3;        nt = f & 7; }
        else        { src = W2; ks = (f - 16) >> 3; nt = (f - 16) & 7; }
        const int kb = ks * 32 + q2 * 8;
        const int c  = nt * 16 + n;
        unsigned int p[4];
        #pragma unroll
        for (int jj = 0; jj < 4; ++jj) {
            unsigned int lo = f2bf(src[(kb + 2 * jj)     * Dm + c]);
            unsigned int hi = f2bf(src[(kb + 2 * jj + 1) * Dm + c]);
            p[jj] = lo | (hi << 16);
        }
        ((uint4*)(ws + WS_WP))[e] = make_uint4(p[0], p[1], p[2], p[3]);
    } else if (bid == 12) {
        const int c = tid & 127, sg = tid >> 7;    // 2 segments
        {
            float s = 0.f;
            #pragma unroll 8
            for (int j0 = 0; j0 < 64; ++j0) {
                const int j = sg * 64 + j0;
                s += embed[j] * Wq[j * 128 + c];
            }
            pp[tid] = s;
        }
        __syncthreads();
        if (tid < 128) qv[tid] = bq[tid] + pp[tid] + pp[128 + tid];
        __syncthreads();
        {   // wkq: head = sg, both heads concurrent
            float s = 0.f;
            #pragma unroll 8
            for (int dh = 0; dh < 64; ++dh)
                s += Wk[c * 128 + sg * 64 + dh] * qv[sg * 64 + dh];
            ws[WS_WKQ + sg * 128 + c] = s;
        }
        if (tid < 2) {
            float s = 0.f;
            for (int dh = 0; dh < 64; ++dh) s += bk[tid * 64 + dh] * qv[tid * 64 + dh];
            ws[WS_BKQ + tid] = s;
        }
    } else if (bid == 13) {
        for (int idx = WS_CNT + tid; idx < WS_WP; idx += 256) ws[idx] = 0.f;
    } else if (bid < 30) {
        // M prefold: 16 blocks x 256 thr x 8 outputs = 32768 = 256x128
        const int base = (bid - 14) * 256 + tid;   // 0..4095
        #pragma unroll
        for (int k = 0; k < 8; ++k) {
            const int o  = base + 4096 * k;
            const int hd = o >> 7, i = o & 127;
            const int h = hd >> 7, d = hd & 127;
            float acc = 0.f;
            #pragma unroll 8
            for (int c64 = 0; c64 < 64; ++c64)
                acc += Wv[d * 128 + h * 64 + c64] * Wo[(h * 64 + c64) * 128 + i];
            ws[WS_M + o] = acc * (1.0f / 4096.0f);
        }
    } else if (bid == 30) {
        if (tid < 256) {
            const int h = tid >> 7, i = tid & 127;
            float acc = 0.f;
            #pragma unroll 8
            for (int c64 = 0; c64 < 64; ++c64)
                acc += bv[h * 64 + c64] * Wo[(h * 64 + c64) * 128 + i];
            ws[WS_VB + tid] = acc * (1.0f / 4096.0f);
        }
    } else {
        // out init: 32 batches x 128 = 4096 floats
        for (int o = tid; o < Bsz * 128; o += 256) out[o] = bo[o & 127];
    }
}

// K1: R14's verified chassis (132.7us e2e, session best) + HW packed bf16
// conversion at both hot pack sites.
//   R15 falsified the barrier-convoy theory: pair-local syncs changed nothing
//   (134.9 vs 132.7) -> the residual is per-wave serial-chain latency, and
//   __syncthreads is restored (simpler, measured-equal-or-better).
//   cvt_pk cuts ~168 VALU insts/wave-iter from the conversion paths
//   (u->a-frag: 128->16; gelu->h1 pack: 64->8), bit-identical RNE.
//   Per-block output-space epilogue unchanged (R14: out is linear in (S,A);
//   each block atomicAdds S_blk @ M + aA_blk . vb; no finisher, no K2).
__global__ __launch_bounds__(512) void mlp_pool_kernel(
    const float* __restrict__ u,  const float* __restrict__ b1,
    const float* __restrict__ b2, float* __restrict__ ws,
    float* __restrict__ out)
{
    __shared__ short lds_w[48 * 512];          // 48 KB weight fragments (both layers)
    __shared__ short lds_h1[4 * 16 * H1STR];   // 4 pair tiles x 16 x 136 bf16 (17.4 KB)
    __shared__ float a2buf[4][16][2][2];       // [pair][row][head][half] (1 KB)
    __shared__ float b1_lds[128];

    const int tid  = threadIdx.x;
    const int wave = tid >> 6;
    const int lane = tid & 63;
    const int quad = lane >> 4;
    const int n15  = lane & 15;
    const int p    = wave >> 1;     // tile pair 0..3
    const int hf   = wave & 1;      // column half

    // stage all weight fragments global(L2) -> LDS (48 KB, 6 float4/thread)
    {
        const float4* src = (const float4*)(ws + WS_WP);
        float4* dst = (float4*)lds_w;
        #pragma unroll
        for (int i = 0; i < 6; ++i) dst[tid + 512 * i] = src[tid + 512 * i];
        if (tid < 128) b1_lds[tid] = b1[tid];
    }

    // per-lane constants for this wave's column half (layer-2 C layout)
    float b2c[4], wkq0[4], wkq1[4];
    #pragma unroll
    for (int nt = 0; nt < 4; ++nt) {
        const int c = hf * 64 + nt * 16 + n15;
        b2c[nt]  = b2[c];
        wkq0[nt] = ws[WS_WKQ + c];
        wkq1[nt] = ws[WS_WKQ + 128 + c];
    }
    const float bkq0 = ws[WS_BKQ];
    const float bkq1 = ws[WS_BKQ + 1];
    __syncthreads();

    const int bb = blockIdx.x >> 4;          // batch
    const int jb = blockIdx.x & 15;          // 256-row chunk within batch
    short* h1t = lds_h1 + p * 16 * H1STR;    // pair-shared tile

    float s0p[4], s1p[4];
    #pragma unroll
    for (int nt = 0; nt < 4; ++nt) { s0p[nt] = 0.f; s1p[nt] = 0.f; }
    float aA0 = 0.f, aA1 = 0.f;

    // iter-0 u loads: lane (quad,n15) = row n15 of pair tile, k quad*8..+8, +32
    const float* ub = u + ((size_t)(bb * Nn + jb * 256 + p * 16 + n15)) * DU + quad * 8;
    float4 f0 = *(const float4*)(ub);
    float4 f1 = *(const float4*)(ub + 4);
    float4 f2 = *(const float4*)(ub + 32);
    float4 f3 = *(const float4*)(ub + 36);

    #pragma unroll 1            // keep rolled
    for (int it = 0; it < 4; ++it) {
        // u tile -> bf16 a-frags via 8 cvt_pk (was ~128 VALU insts)
        unsigned int ua[4], ub4[4];
        ua[0]  = pk_bf16(f0.x, f0.y); ua[1]  = pk_bf16(f0.z, f0.w);
        ua[2]  = pk_bf16(f1.x, f1.y); ua[3]  = pk_bf16(f1.z, f1.w);
        ub4[0] = pk_bf16(f2.x, f2.y); ub4[1] = pk_bf16(f2.z, f2.w);
        ub4[2] = pk_bf16(f3.x, f3.y); ub4[3] = pk_bf16(f3.z, f3.w);
        frag_ab a0 = *(const frag_ab*)ua;
        frag_ab a1 = *(const frag_ab*)ub4;

        // ---- layer 1, TRANSPOSED: D = W1^T-tile(16c x 64k) . u^T(64k x 16m)
        #pragma unroll
        for (int i = 0; i < 4; ++i) {
            const int ct = hf * 4 + i;
            float4 bi = *(const float4*)&b1_lds[ct * 16 + quad * 4];
            frag_cd acc = (frag_cd){bi.x, bi.y, bi.z, bi.w};       // bias folded
            frag_ab w0 = *(const frag_ab*)&lds_w[(ct)     * 512 + lane * 8];  // ks=0
            acc = __builtin_amdgcn_mfma_f32_16x16x32_bf16(w0, a0, acc, 0, 0, 0);
            frag_ab w1 = *(const frag_ab*)&lds_w[(8 + ct) * 512 + lane * 8];  // ks=1
            acc = __builtin_amdgcn_mfma_f32_16x16x32_bf16(w1, a1, acc, 0, 0, 0);
            // gelu -> packed bf16 x4 via 2 cvt_pk -> one ds_write_b64
            unsigned int lo = pk_bf16(gelu_fast(acc[0]), gelu_fast(acc[1]));
            unsigned int hi = pk_bf16(gelu_fast(acc[2]), gelu_fast(acc[3]));
            *(uint2*)&h1t[n15 * H1STR + ct * 16 + quad * 4] = make_uint2(lo, hi);
        }
        __syncthreads();    // B1: both halves' h1 visible (8-wave domain)

        // prefetch next iter's u AFTER B1: drains at B2 behind layer2+alpha
        if (it < 3) {
            const float* un = ub + (size_t)((it + 1) * 64) * DU;
            f0 = *(const float4*)(un);
            f1 = *(const float4*)(un + 4);
            f2 = *(const float4*)(un + 32);
            f3 = *(const float4*)(un + 36);
        }

        // ---- layer 2 (this half's 64 cols): M16 N64 K128, B from LDS
        frag_cd acc2[4];
        #pragma unroll
        for (int nt = 0; nt < 4; ++nt)
            acc2[nt] = (frag_cd){b2c[nt], b2c[nt], b2c[nt], b2c[nt]};  // bias folded
        #pragma unroll
        for (int ks = 0; ks < 4; ++ks) {
            frag_ab a2 = *(const frag_ab*)&h1t[n15 * H1STR + ks * 32 + quad * 8];
            #pragma unroll
            for (int nt = 0; nt < 4; ++nt) {
                frag_ab w2f = *(const frag_ab*)&lds_w[(16 + ks * 8 + hf * 4 + nt) * 512 + lane * 8];
                acc2[nt] = __builtin_amdgcn_mfma_f32_16x16x32_bf16(a2, w2f, acc2[nt], 0, 0, 0);
            }
        }

        // gelu -> z (this half) fp32 in registers
        #pragma unroll
        for (int nt = 0; nt < 4; ++nt) {
            #pragma unroll
            for (int r = 0; r < 4; ++r)
                acc2[nt][r] = gelu_fast(acc2[nt][r]);
        }

        // ---- half-alpha dots, reduce over n15 lanes, publish to a2buf
        float p0[4], p1[4];
        #pragma unroll
        for (int r = 0; r < 4; ++r) { p0[r] = 0.f; p1[r] = 0.f; }
        #pragma unroll
        for (int nt = 0; nt < 4; ++nt) {
            #pragma unroll
            for (int r = 0; r < 4; ++r) {
                p0[r] += acc2[nt][r] * wkq0[nt];
                p1[r] += acc2[nt][r] * wkq1[nt];
            }
        }
        #pragma unroll
        for (int r = 0; r < 4; ++r) {
            #pragma unroll
            for (int d = 1; d < 16; d <<= 1) {
                p0[r] += __shfl_xor(p0[r], d);
                p1[r] += __shfl_xor(p1[r], d);
            }
        }
        if (n15 == 0) {
            #pragma unroll
            for (int r = 0; r < 4; ++r) {
                const int row = quad * 4 + r;
                a2buf[p][row][0][hf] = p0[r];
                a2buf[p][row][1][hf] = p1[r];
            }
        }
        __syncthreads();    // B2: alpha halves visible (also protects h1/a2buf reuse)

        // ---- full alpha for my rows; accumulate S (my cols, z in acc2) and A
        #pragma unroll
        for (int r = 0; r < 4; ++r) {
            const int row = quad * 4 + r;
            const float al0 = a2buf[p][row][0][0] + a2buf[p][row][0][1] + bkq0;
            const float al1 = a2buf[p][row][1][0] + a2buf[p][row][1][1] + bkq1;
            #pragma unroll
            for (int nt = 0; nt < 4; ++nt) {
                s0p[nt] += al0 * acc2[nt][r];
                s1p[nt] += al1 * acc2[nt][r];
            }
            aA0 += al0; aA1 += al1;
        }
    }

    // cross-quad reduce: after xor16+xor32 ALL lanes hold the pair-total
    #pragma unroll
    for (int nt = 0; nt < 4; ++nt) {
        s0p[nt] += __shfl_xor(s0p[nt], 16); s0p[nt] += __shfl_xor(s0p[nt], 32);
        s1p[nt] += __shfl_xor(s1p[nt], 16); s1p[nt] += __shfl_xor(s1p[nt], 32);
    }
    aA0 += __shfl_xor(aA0, 16); aA0 += __shfl_xor(aA0, 32);
    aA1 += __shfl_xor(aA1, 16); aA1 += __shfl_xor(aA1, 32);

    // ---- per-block output-space epilogue (no counter, no finisher, no K2)
    // lds_h1 scratch (4352 floats): sw[0..1023]=[pair][256], aw[1024..1031],
    // Sb[1032..1287], part[1288..1799]
    float* sw   = (float*)lds_h1;
    float* aw   = sw + 1024;
    float* Sb   = sw + 1032;
    float* part = sw + 1288;

    __syncthreads();        // block-wide: all pairs done with h1t before reuse

    if (quad == 0) {        // 16 lanes x 4 nt x 2 heads per wave
        #pragma unroll
        for (int nt = 0; nt < 4; ++nt) {
            const int c = hf * 64 + nt * 16 + n15;
            sw[p * 256 + c]       = s0p[nt];
            sw[p * 256 + 128 + c] = s1p[nt];
        }
        if (hf == 0 && lane == 0) { aw[p * 2] = aA0; aw[p * 2 + 1] = aA1; }
    }
    __syncthreads();

    if (tid < 256)
        Sb[tid] = sw[tid] + sw[256 + tid] + sw[512 + tid] + sw[768 + tid];
    __syncthreads();

    {   // contrib = Sb(1x256) @ M(256x128), 4-way split-K over 512 threads
        const int i = tid & 127, seg = tid >> 7;
        float acc = 0.f;
        #pragma unroll 8
        for (int k = 0; k < 64; ++k) {
            const int hd = seg * 64 + k;
            acc += Sb[hd] * ws[WS_M + hd * 128 + i];
        }
        part[tid] = acc;
    }
    __syncthreads();

    if (tid < 128) {
        const float aT0 = aw[0] + aw[2] + aw[4] + aw[6];
        const float aT1 = aw[1] + aw[3] + aw[5] + aw[7];
        atomicAdd(&out[bb * 128 + tid],
                  part[tid] + part[128 + tid] + part[256 + tid] + part[384 + tid]
                  + aT0 * ws[WS_VB + tid] + aT1 * ws[WS_VB + 128 + tid]);
    }
}

extern "C" void kernel_launch(void* const* d_in, const int* in_sizes, int n_in,
                              void* d_out, int out_size, void* d_ws, size_t ws_size,
                              hipStream_t stream) {
    const float* u     = (const float*)d_in[0];
    // d_in[1] = x : unused by the reference
    const float* W1    = (const float*)d_in[2];
    const float* b1    = (const float*)d_in[3];
    const float* W2    = (const float*)d_in[4];
    const float* b2    = (const float*)d_in[5];
    const float* embed = (const float*)d_in[6];
    const float* Wq    = (const float*)d_in[7];
    const float* bq    = (const float*)d_in[8];
    const float* Wk    = (const float*)d_in[9];
    const float* bk    = (const float*)d_in[10];
    const float* Wv    = (const float*)d_in[11];
    const float* bv    = (const float*)d_in[12];
    const float* Wo    = (const float*)d_in[13];
    const float* bo    = (const float*)d_in[14];
    float* ws  = (float*)d_ws;
    float* out = (float*)d_out;

    hipLaunchKernelGGL(precompute_kernel, dim3(32), dim3(256), 0, stream,
                       embed, Wq, bq, Wk, bk, W1, W2, Wv, bv, Wo, bo, ws, out);
    hipLaunchKernelGGL(mlp_pool_kernel, dim3(GRID_MLP), dim3(512), 0, stream,
                       u, b1, b2, ws, out);
}